// Round 3
// baseline (323.744 us; speedup 1.0000x reference)
//
#include <hip/hip_runtime.h>

#define LT_N 8192
#define CHUNK 2048   // floats per wave-chunk (8 KB)

// Lower-triangular matvec y[i] = sum_{j<=i} W[i,j]*x[j], N=8192.
// One block (4 waves) per row; wave w scans columns [w*2048,(w+1)*2048)
// clipped to row length. 8 independent float4 loads issued per wave
// (fully unrolled) -> deep MLP; x read straight from global (L2-hot,
// no intra-block reuse so LDS staging would only add latency).
__global__ __launch_bounds__(256, 4) void tril_matvec_kernel(
    const float* __restrict__ x,
    const float* __restrict__ W,
    float* __restrict__ y)
{
    __shared__ float partial[4];

    const int wave = threadIdx.x >> 6;
    const int lane = threadIdx.x & 63;
    const int r = LT_N - 1 - (int)blockIdx.x;   // longest rows first
    const int len = r + 1;
    const float* Wr = W + (size_t)r * LT_N;

    const int beg = wave * CHUNK;
    const int end = min(beg + CHUNK, len);

    float acc = 0.0f;
    if (beg < len) {
        const int n = end - beg;               // 1..2048
        if (n == CHUNK) {
            // Full chunk: 8 W-loads + 8 x-loads, all independent, then FMAs.
            const float* Wb = Wr + beg + lane * 4;
            const float* xb = x  + beg + lane * 4;
            float4 wv[8], xv[8];
            #pragma unroll
            for (int i = 0; i < 8; ++i) wv[i] = *(const float4*)(Wb + i * 256);
            #pragma unroll
            for (int i = 0; i < 8; ++i) xv[i] = *(const float4*)(xb + i * 256);
            #pragma unroll
            for (int i = 0; i < 8; ++i)
                acc += wv[i].x * xv[i].x + wv[i].y * xv[i].y
                     + wv[i].z * xv[i].z + wv[i].w * xv[i].w;
        } else {
            // Boundary chunk (only the last active wave of short-ish rows).
            const int n4 = n & ~3;
            for (int j = lane * 4; j < n4; j += 256) {
                float4 wv = *(const float4*)(Wr + beg + j);
                float4 xv = *(const float4*)(x  + beg + j);
                acc += wv.x * xv.x + wv.y * xv.y + wv.z * xv.z + wv.w * xv.w;
            }
            const int rem = n - n4;
            if (lane < rem)
                acc += Wr[beg + n4 + lane] * x[beg + n4 + lane];
        }
    }

    // Wave64 tree reduction.
    #pragma unroll
    for (int off = 32; off > 0; off >>= 1)
        acc += __shfl_down(acc, off, 64);

    if (lane == 0) partial[wave] = acc;      // inactive waves write 0
    __syncthreads();
    if (threadIdx.x == 0)
        y[r] = (partial[0] + partial[1]) + (partial[2] + partial[3]);
}

extern "C" void kernel_launch(void* const* d_in, const int* in_sizes, int n_in,
                              void* d_out, int out_size, void* d_ws, size_t ws_size,
                              hipStream_t stream)
{
    const float* x = (const float*)d_in[0];
    const float* W = (const float*)d_in[1];
    float* y = (float*)d_out;

    dim3 grid(LT_N);    // one block per row
    dim3 block(256);    // 4 waves
    tril_matvec_kernel<<<grid, block, 0, stream>>>(x, W, y);
}